// Round 2
// baseline (2268.177 us; speedup 1.0000x reference)
//
#include <hip/hip_runtime.h>
#include <hip/hip_bf16.h>

// MambaEncoder on MI355X — v2: ~130 MiB workspace (was ~538 MB -> suspected OOB crash).
//   prep: weights fp32->bf16 (+ sp_w transpose), decay = exp(-mean(exp(A_log)))
//   k_in_proj: h = gelu(LN(x @ in_w^T + in_b))           -> h bf16 [262144][256]
//   k_layer (x2, one block per sequence n, 8 k-blocks of 64 rows each):
//     z=LN(h); xg=silu(z@gate^T+b) [kept in regs]; s=xg@sp^T+b [LDS];
//     EXACT sequential scan (state in reg across k-blocks, carried across layers
//     via 512KB state_buf); y=states@sp_w + D*xg; h += y@op^T + op_b
//   k_out: out = gelu(LN(h[:,511,:] @ out_w^T + out_b))

typedef __attribute__((ext_vector_type(8))) __bf16 bf16x8;
typedef __attribute__((ext_vector_type(8))) short short8;
typedef __attribute__((ext_vector_type(4))) float f32x4;

#define NSEQ 512
#define KSEQ 512
#define FIN 96
#define DMODEL 256
#define MTOT (NSEQ*KSEQ)

__device__ __forceinline__ unsigned short f2bf(float f){
  union { float f; unsigned u; } v; v.f = f;
  unsigned r = (v.u + 0x7FFFu + ((v.u >> 16) & 1u)) >> 16;
  return (unsigned short)r;
}
__device__ __forceinline__ float bf2f(unsigned short b){
  union { unsigned u; float f; } v; v.u = ((unsigned)b) << 16; return v.f;
}
__device__ __forceinline__ float gelu_f(float x){
  return 0.5f * x * (1.0f + erff(x * 0.70710678118654752440f));
}
__device__ __forceinline__ float silu_f(float x){
  return x / (1.0f + __expf(-x));
}
// XOR swizzle: row stride multiple of 128B keeps it bijective (bits 4-6 in-row)
__device__ __forceinline__ unsigned swzA(int row, int kbyte){   // [64][256] bf16, 512B stride
  return ((unsigned)(row*512 + kbyte)) ^ (unsigned)((row & 7) << 4);
}
__device__ __forceinline__ unsigned swzB(int n, int kbyte){     // [256][64] bf16, 128B stride
  return ((unsigned)(n*128 + kbyte)) ^ (unsigned)((n & 7) << 4);
}

__device__ __forceinline__ void zero_acc(f32x4 (&acc)[4][4]){
  #pragma unroll
  for(int a=0;a<4;++a)
    #pragma unroll
    for(int b=0;b<4;++b)
      acc[a][b] = (f32x4){0.f,0.f,0.f,0.f};
}

// acc[4][4] += A_lds[64][KCH*64] (bf16, swzA) @ W[256][KCH*64]^T (staged to Bs, swzB)
// wave w owns output cols [w*64, w*64+64)
template<int KCH>
__device__ __forceinline__ void gemm_64x256(const unsigned short* __restrict__ wb,
                                            char* As, char* Bs,
                                            f32x4 (&acc)[4][4], int tid)
{
  const int lane = tid & 63;
  const int c0   = (tid >> 6) * 64;
  const int lr   = lane & 15;
  const int lk16 = (lane >> 4) * 16;
  #pragma unroll
  for(int kc = 0; kc < KCH; ++kc){
    __syncthreads();
    {
      const unsigned short* src = wb + (size_t)tid * (KCH*64) + kc*64;
      #pragma unroll
      for(int i = 0; i < 8; ++i){
        short8 v = *(const short8*)(src + i*8);
        *(short8*)(Bs + swzB(tid, i*16)) = v;
      }
    }
    __syncthreads();
    #pragma unroll
    for(int t2 = 0; t2 < 2; ++t2){
      bf16x8 af[4], bfr[4];
      #pragma unroll
      for(int fr = 0; fr < 4; ++fr)
        af[fr] = *(const bf16x8*)(As + swzA(fr*16 + lr, kc*128 + t2*64 + lk16));
      #pragma unroll
      for(int fc = 0; fc < 4; ++fc)
        bfr[fc] = *(const bf16x8*)(Bs + swzB(c0 + fc*16 + lr, t2*64 + lk16));
      #pragma unroll
      for(int fr = 0; fr < 4; ++fr)
        #pragma unroll
        for(int fc = 0; fc < 4; ++fc)
          acc[fr][fc] = __builtin_amdgcn_mfma_f32_16x16x32_bf16(af[fr], bfr[fc], acc[fr][fc], 0, 0, 0);
    }
  }
}

// ---------------- prep kernels ----------------
__global__ void k_cvt(const float* __restrict__ s, unsigned short* __restrict__ d, int n){
  int i = blockIdx.x*256 + threadIdx.x;
  if(i < n) d[i] = f2bf(s[i]);
}
__global__ void k_cvt_inw(const float* __restrict__ w, unsigned short* __restrict__ d){
  int i = blockIdx.x*256 + threadIdx.x;   // 32768: [256][128] zero-padded K
  int n = i >> 7, f = i & 127;
  d[i] = (f < 96) ? f2bf(w[n*96 + f]) : (unsigned short)0;
}
__global__ void k_spT(const float* __restrict__ spw, unsigned short* __restrict__ d){
  int l = blockIdx.y;
  int i = blockIdx.x*256 + threadIdx.x;   // 65536: [d][s] = sp_w[s][d]
  int dd = i >> 8, ss = i & 255;
  d[l*65536 + i] = f2bf(spw[l*65536 + ss*256 + dd]);
}
__global__ void k_decay(const float* __restrict__ A_log, float* __restrict__ decay){
  int l = blockIdx.x, d = threadIdx.x;
  const float* row = A_log + ((size_t)l*256 + d)*256;
  float acc = 0.f;
  for(int s = 0; s < 256; ++s) acc += expf(row[s]);
  decay[l*256 + d] = expf(-acc * (1.f/256.f));
}

// ---------------- h = gelu(LN(x @ in_w^T + in_b)) -> bf16 ----------------
__global__ __launch_bounds__(256) void k_in_proj(
    const float* __restrict__ x_g,
    const unsigned short* __restrict__ in_wb,
    const float* __restrict__ in_b,
    const float* __restrict__ ln_gv, const float* __restrict__ ln_bv,
    unsigned short* __restrict__ h_g)
{
  __shared__ char smem[65536];
  char* As = smem; char* Bs = smem + 32768;
  const int tid = threadIdx.x;
  const int m0 = blockIdx.x * 64;
  const int lane = tid & 63, c0w = (tid>>6)*64, lr = lane & 15, rb = (lane>>4)*4;
  // stage A: x bf16 + zero pad 96->128
  {
    const int r = tid >> 2, cq = tid & 3;
    const float* src = x_g + (size_t)(m0 + r)*FIN + cq*24;
    unsigned short tmp[24] __attribute__((aligned(16)));
    #pragma unroll
    for(int i = 0; i < 6; ++i){
      float4 v = *(const float4*)(src + i*4);
      tmp[4*i]=f2bf(v.x); tmp[4*i+1]=f2bf(v.y); tmp[4*i+2]=f2bf(v.z); tmp[4*i+3]=f2bf(v.w);
    }
    #pragma unroll
    for(int i = 0; i < 3; ++i)
      *(short8*)(As + swzA(r, cq*48 + i*16)) = *(const short8*)(tmp + i*8);
    if(cq == 3){
      short8 z8 = {0,0,0,0,0,0,0,0};
      #pragma unroll
      for(int i = 0; i < 4; ++i)
        *(short8*)(As + swzA(r, 192 + i*16)) = z8;
    }
  }
  f32x4 acc[4][4]; zero_acc(acc);
  gemm_64x256<2>(in_wb, As, Bs, acc, tid);
  __syncthreads();
  // acc + b -> fp32 LDS [64][256] (1024B rows, swizzled)
  #pragma unroll
  for(int fc = 0; fc < 4; ++fc){
    const int col = c0w + fc*16 + lr;
    const float bb = in_b[col];
    #pragma unroll
    for(int fr = 0; fr < 4; ++fr)
      #pragma unroll
      for(int rg = 0; rg < 4; ++rg){
        const int row = fr*16 + rb + rg;
        *(float*)(smem + (((unsigned)(row*1024 + col*4)) ^ ((row&7)<<4))) = acc[fr][fc][rg] + bb;
      }
  }
  __syncthreads();
  // LN + gelu -> bf16 store
  {
    const int r = tid >> 2, c0 = (tid & 3) * 64;
    float vals[64]; float sm = 0.f, sq = 0.f;
    #pragma unroll
    for(int i = 0; i < 16; ++i){
      float4 v = *(const float4*)(smem + (((unsigned)(r*1024 + (c0 + i*4)*4)) ^ ((r&7)<<4)));
      vals[4*i]=v.x; vals[4*i+1]=v.y; vals[4*i+2]=v.z; vals[4*i+3]=v.w;
    }
    #pragma unroll
    for(int i = 0; i < 64; ++i){ sm += vals[i]; sq += vals[i]*vals[i]; }
    sm += __shfl_xor(sm, 1); sm += __shfl_xor(sm, 2);
    sq += __shfl_xor(sq, 1); sq += __shfl_xor(sq, 2);
    const float mu = sm * (1.f/256.f);
    const float rstd = rsqrtf(sq * (1.f/256.f) - mu*mu + 1e-5f);
    unsigned short* dst = h_g + (size_t)(m0 + r)*DMODEL + c0;
    #pragma unroll
    for(int i = 0; i < 8; ++i){
      short8 o;
      #pragma unroll
      for(int j = 0; j < 8; ++j){
        const int c = c0 + i*8 + j;
        o[j] = (short)f2bf(gelu_f((vals[i*8+j]-mu)*rstd*ln_gv[c] + ln_bv[c]));
      }
      *(short8*)(dst + i*8) = o;
    }
  }
}

// ---------------- full layer, one block per sequence n ----------------
__global__ __launch_bounds__(256) void k_layer(
    unsigned short* __restrict__ h_g,
    const unsigned short* __restrict__ gate_wb,
    const unsigned short* __restrict__ sp_wb,
    const unsigned short* __restrict__ sp_wTb,
    const unsigned short* __restrict__ op_wb,
    const float* __restrict__ ln_gv, const float* __restrict__ ln_bv,
    const float* __restrict__ gate_bv, const float* __restrict__ sp_bv,
    const float* __restrict__ decay_v, const float* __restrict__ D_v,
    const float* __restrict__ op_bv,
    float* __restrict__ state_buf, const int layer)
{
  __shared__ char smem[65536];
  char* As = smem; char* Bs = smem + 32768;
  const int tid = threadIdx.x;
  const int n = blockIdx.x;
  const int lane = tid & 63, c0w = (tid>>6)*64, lr = lane & 15, rb = (lane>>4)*4;
  const float dc = decay_v[tid];
  float st = (layer > 0) ? state_buf[n*256 + tid] : 0.f;

  #pragma unroll 1
  for(int kb = 0; kb < 8; ++kb){
    const int m0 = n*KSEQ + kb*64;
    // ---- LN(h) -> z bf16 in As ----
    {
      const int r = tid >> 2, c0 = (tid & 3) * 64;
      const unsigned short* src = h_g + (size_t)(m0 + r)*DMODEL + c0;
      short8 hv[8];
      #pragma unroll
      for(int i = 0; i < 8; ++i) hv[i] = *(const short8*)(src + i*8);
      float sm = 0.f, sq = 0.f;
      #pragma unroll
      for(int i = 0; i < 8; ++i)
        #pragma unroll
        for(int j = 0; j < 8; ++j){
          float v = bf2f((unsigned short)hv[i][j]); sm += v; sq += v*v;
        }
      sm += __shfl_xor(sm, 1); sm += __shfl_xor(sm, 2);
      sq += __shfl_xor(sq, 1); sq += __shfl_xor(sq, 2);
      const float mu = sm * (1.f/256.f);
      const float rstd = rsqrtf(sq * (1.f/256.f) - mu*mu + 1e-5f);
      #pragma unroll
      for(int i = 0; i < 8; ++i){
        short8 z;
        #pragma unroll
        for(int j = 0; j < 8; ++j){
          const int c = c0 + i*8 + j;
          z[j] = (short)f2bf((bf2f((unsigned short)hv[i][j])-mu)*rstd*ln_gv[c] + ln_bv[c]);
        }
        *(short8*)(As + swzA(r, c0*2 + i*16)) = z;
      }
    }
    f32x4 acc[4][4]; zero_acc(acc);
    gemm_64x256<4>(gate_wb, As, Bs, acc, tid);
    __syncthreads();
    // xg = silu(acc+gb) -> regs (same C-fragment layout reused later) + As
    f32x4 xg_reg[4][4];
    #pragma unroll
    for(int fc = 0; fc < 4; ++fc){
      const int col = c0w + fc*16 + lr;
      const float gb = gate_bv[col];
      #pragma unroll
      for(int fr = 0; fr < 4; ++fr)
        #pragma unroll
        for(int rg = 0; rg < 4; ++rg){
          const int row = fr*16 + rb + rg;
          const float v = silu_f(acc[fr][fc][rg] + gb);
          xg_reg[fr][fc][rg] = v;
          *(unsigned short*)(As + swzA(row, col*2)) = f2bf(v);
        }
    }
    zero_acc(acc);
    gemm_64x256<4>(sp_wb, As, Bs, acc, tid);
    __syncthreads();
    // s = acc + sp_b -> As
    #pragma unroll
    for(int fc = 0; fc < 4; ++fc){
      const int col = c0w + fc*16 + lr;
      const float sb = sp_bv[col];
      #pragma unroll
      for(int fr = 0; fr < 4; ++fr)
        #pragma unroll
        for(int rg = 0; rg < 4; ++rg)
          *(unsigned short*)(As + swzA(fr*16 + rb + rg, col*2)) = f2bf(acc[fr][fc][rg] + sb);
    }
    __syncthreads();
    // exact sequential scan: thread = channel, state in register across kb
    #pragma unroll 4
    for(int j = 0; j < 64; ++j){
      const unsigned a = swzA(j, tid*2);
      const float sv = bf2f(*(const unsigned short*)(As + a));
      st = st*dc + sv;
      *(unsigned short*)(As + a) = f2bf(st);
    }
    zero_acc(acc);
    gemm_64x256<4>(sp_wTb, As, Bs, acc, tid);
    __syncthreads();
    // y = acc + D*xg -> As
    #pragma unroll
    for(int fc = 0; fc < 4; ++fc){
      const int col = c0w + fc*16 + lr;
      const float Dv = D_v[col];
      #pragma unroll
      for(int fr = 0; fr < 4; ++fr)
        #pragma unroll
        for(int rg = 0; rg < 4; ++rg)
          *(unsigned short*)(As + swzA(fr*16 + rb + rg, col*2)) =
              f2bf(acc[fr][fc][rg] + Dv*xg_reg[fr][fc][rg]);
    }
    zero_acc(acc);
    gemm_64x256<4>(op_wb, As, Bs, acc, tid);
    __syncthreads();
    // acc + op_b -> As bf16
    #pragma unroll
    for(int fc = 0; fc < 4; ++fc){
      const int col = c0w + fc*16 + lr;
      const float ob = op_bv[col];
      #pragma unroll
      for(int fr = 0; fr < 4; ++fr)
        #pragma unroll
        for(int rg = 0; rg < 4; ++rg)
          *(unsigned short*)(As + swzA(fr*16 + rb + rg, col*2)) = f2bf(acc[fr][fc][rg] + ob);
    }
    __syncthreads();
    // h += (y@op^T + op_b), coalesced RMW
    {
      char* dst = (char*)(h_g + (size_t)m0*DMODEL);
      #pragma unroll
      for(int i = 0; i < 8; ++i){
        const unsigned flat = (unsigned)(i*4096 + tid*16);
        const unsigned row = flat >> 9;
        short8 a = *(const short8*)(As + (flat ^ ((row & 7u) << 4)));
        short8 hv = *(const short8*)(dst + flat);
        short8 o;
        #pragma unroll
        for(int j = 0; j < 8; ++j)
          o[j] = (short)f2bf(bf2f((unsigned short)a[j]) + bf2f((unsigned short)hv[j]));
        *(short8*)(dst + flat) = o;
      }
    }
    __syncthreads();
  }
  state_buf[n*256 + tid] = st;   // layer-0 final state feeds layer-1
}

// ---------------- out = gelu(LN(h[:,511,:] @ out_w^T + out_b)) ----------------
__global__ __launch_bounds__(256) void k_out(
    const unsigned short* __restrict__ h_g,
    const unsigned short* __restrict__ out_wb,
    const float* __restrict__ out_bv,
    const float* __restrict__ ln_gv, const float* __restrict__ ln_bv,
    float* __restrict__ out_g)
{
  __shared__ char smem[65536];
  char* As = smem; char* Bs = smem + 32768;
  const int tid = threadIdx.x;
  const int r0 = blockIdx.x * 64;
  const int lane = tid & 63, c0w = (tid>>6)*64, lr = lane & 15, rb = (lane>>4)*4;
  {
    const int r = tid >> 2, c0 = (tid & 3) * 64;
    const unsigned short* src = h_g + ((size_t)(r0 + r)*KSEQ + (KSEQ-1))*DMODEL + c0;
    #pragma unroll
    for(int i = 0; i < 8; ++i){
      short8 v = *(const short8*)(src + i*8);
      *(short8*)(As + swzA(r, c0*2 + i*16)) = v;
    }
  }
  f32x4 acc[4][4]; zero_acc(acc);
  gemm_64x256<4>(out_wb, As, Bs, acc, tid);
  __syncthreads();
  #pragma unroll
  for(int fc = 0; fc < 4; ++fc){
    const int col = c0w + fc*16 + lr;
    const float bb = out_bv[col];
    #pragma unroll
    for(int fr = 0; fr < 4; ++fr)
      #pragma unroll
      for(int rg = 0; rg < 4; ++rg){
        const int row = fr*16 + rb + rg;
        *(float*)(smem + (((unsigned)(row*1024 + col*4)) ^ ((row&7)<<4))) = acc[fr][fc][rg] + bb;
      }
  }
  __syncthreads();
  {
    const int r = tid >> 2, c0 = (tid & 3) * 64;
    float vals[64]; float sm = 0.f, sq = 0.f;
    #pragma unroll
    for(int i = 0; i < 16; ++i){
      float4 v = *(const float4*)(smem + (((unsigned)(r*1024 + (c0 + i*4)*4)) ^ ((r&7)<<4)));
      vals[4*i]=v.x; vals[4*i+1]=v.y; vals[4*i+2]=v.z; vals[4*i+3]=v.w;
    }
    #pragma unroll
    for(int i = 0; i < 64; ++i){ sm += vals[i]; sq += vals[i]*vals[i]; }
    sm += __shfl_xor(sm, 1); sm += __shfl_xor(sm, 2);
    sq += __shfl_xor(sq, 1); sq += __shfl_xor(sq, 2);
    const float mu = sm * (1.f/256.f);
    const float rstd = rsqrtf(sq * (1.f/256.f) - mu*mu + 1e-5f);
    float* dst = out_g + (size_t)(r0 + r)*DMODEL + c0;
    #pragma unroll
    for(int i = 0; i < 16; ++i){
      float4 o;
      o.x = gelu_f((vals[4*i+0]-mu)*rstd*ln_gv[c0+i*4+0] + ln_bv[c0+i*4+0]);
      o.y = gelu_f((vals[4*i+1]-mu)*rstd*ln_gv[c0+i*4+1] + ln_bv[c0+i*4+1]);
      o.z = gelu_f((vals[4*i+2]-mu)*rstd*ln_gv[c0+i*4+2] + ln_bv[c0+i*4+2]);
      o.w = gelu_f((vals[4*i+3]-mu)*rstd*ln_gv[c0+i*4+3] + ln_bv[c0+i*4+3]);
      *(float4*)(dst + i*4) = o;
    }
  }
}

extern "C" void kernel_launch(void* const* d_in, const int* in_sizes, int n_in,
                              void* d_out, int out_size, void* d_ws, size_t ws_size,
                              hipStream_t stream) {
  (void)in_sizes; (void)n_in; (void)out_size; (void)ws_size;
  const float* x        = (const float*)d_in[0];
  const float* in_w     = (const float*)d_in[1];
  const float* in_b     = (const float*)d_in[2];
  const float* in_ln_g  = (const float*)d_in[3];
  const float* in_ln_b  = (const float*)d_in[4];
  const float* ln_g     = (const float*)d_in[5];
  const float* ln_b     = (const float*)d_in[6];
  const float* gate_w   = (const float*)d_in[7];
  const float* gate_b   = (const float*)d_in[8];
  const float* sp_w     = (const float*)d_in[9];
  const float* sp_b     = (const float*)d_in[10];
  const float* op_w     = (const float*)d_in[11];
  const float* op_b     = (const float*)d_in[12];
  const float* A_log    = (const float*)d_in[13];
  const float* Dp       = (const float*)d_in[14];
  const float* out_w    = (const float*)d_in[15];
  const float* out_b    = (const float*)d_in[16];
  const float* out_ln_g = (const float*)d_in[17];
  const float* out_ln_b = (const float*)d_in[18];

  char* ws = (char*)d_ws;
  // ~130 MiB workspace
  unsigned short* h_g       = (unsigned short*)(ws + 0);           // 128 MiB bf16
  float*          state_buf = (float*)(ws + 134217728);            // 512 KiB
  float*          decay     = (float*)(ws + 134742016);            // 2 KiB
  unsigned short* wbase     = (unsigned short*)(ws + 134744064);   // ~1.2 MiB
  unsigned short* in_wb  = wbase;               // 32768
  unsigned short* gate_wb= in_wb  + 32768;      // 2*65536
  unsigned short* sp_wb  = gate_wb+ 131072;
  unsigned short* sp_wTb = sp_wb  + 131072;
  unsigned short* op_wb  = sp_wTb + 131072;
  unsigned short* out_wb = op_wb  + 131072;     // 65536

  // prep
  k_cvt_inw<<<128, 256, 0, stream>>>(in_w, in_wb);
  k_cvt<<<512, 256, 0, stream>>>(gate_w, gate_wb, 131072);
  k_cvt<<<512, 256, 0, stream>>>(sp_w,   sp_wb,   131072);
  k_cvt<<<512, 256, 0, stream>>>(op_w,   op_wb,   131072);
  k_cvt<<<256, 256, 0, stream>>>(out_w,  out_wb,  65536);
  k_spT<<<dim3(256,2), 256, 0, stream>>>(sp_w, sp_wTb);
  k_decay<<<2, 256, 0, stream>>>(A_log, decay);

  // pipeline
  k_in_proj<<<MTOT/64, 256, 0, stream>>>(x, in_wb, in_b, in_ln_g, in_ln_b, h_g);
  for(int l = 0; l < 2; ++l){
    k_layer<<<NSEQ, 256, 0, stream>>>(h_g,
        gate_wb + l*65536, sp_wb + l*65536, sp_wTb + l*65536, op_wb + l*65536,
        ln_g + l*256, ln_b + l*256, gate_b + l*256, sp_b + l*256,
        decay + l*256, Dp + l*256, op_b + l*256, state_buf, l);
  }
  k_out<<<NSEQ/64, 256, 0, stream>>>(h_g, out_wb, out_b, out_ln_g, out_ln_b, (float*)d_out);
}

// Round 4
// 1797.564 us; speedup vs baseline: 1.2618x; 1.2618x over previous
//
#include <hip/hip_runtime.h>
#include <hip/hip_bf16.h>

// MambaEncoder on MI355X — v4: back to proven <=134MiB workspace.
//   per layer: k_seed (read-only h): recompute s-tile, emit 256-float scan seed
//              for the NEXT tile (4MiB seed_buf instead of 64MiB s_buf);
//              k_tile: recompute s (bit-identical), scan(seed), spT, y=+D*xg(fp32),
//              op, single h-RMW. v2-verbatim epilogues; barrier-free waveB GEMMs.

typedef __attribute__((ext_vector_type(8))) __bf16 bf16x8;
typedef __attribute__((ext_vector_type(8))) short short8;
typedef __attribute__((ext_vector_type(4))) float f32x4;

#define NSEQ 512
#define KSEQ 512
#define FIN 96
#define DMODEL 256
#define MTOT (NSEQ*KSEQ)

__device__ __forceinline__ unsigned short f2bf(float f){
  union { float f; unsigned u; } v; v.f = f;
  unsigned r = (v.u + 0x7FFFu + ((v.u >> 16) & 1u)) >> 16;
  return (unsigned short)r;
}
__device__ __forceinline__ float bf2f(unsigned short b){
  union { unsigned u; float f; } v; v.u = ((unsigned)b) << 16; return v.f;
}
__device__ __forceinline__ float gelu_f(float x){
  return 0.5f * x * (1.0f + erff(x * 0.70710678118654752440f));
}
__device__ __forceinline__ float silu_f(float x){
  return x / (1.0f + __expf(-x));
}
__device__ __forceinline__ unsigned swzA(int row, int kbyte){   // [64][256] bf16, 512B stride
  return ((unsigned)(row*512 + kbyte)) ^ (unsigned)((row & 7) << 4);
}
__device__ __forceinline__ unsigned swzB(int n, int kbyte){     // [256][64] bf16
  return ((unsigned)(n*128 + kbyte)) ^ (unsigned)((n & 7) << 4);
}

__device__ __forceinline__ void zero_acc(f32x4 (&acc)[4][4]){
  #pragma unroll
  for(int a=0;a<4;++a)
    #pragma unroll
    for(int b=0;b<4;++b)
      acc[a][b] = (f32x4){0.f,0.f,0.f,0.f};
}

// per-wave GEMM K=256: acc += As(64x256 bf16, swzA) @ W[256][256]^T, B direct from global
__device__ __forceinline__ void gemm_waveB(const unsigned short* __restrict__ wb,
                                           const char* As, f32x4 (&acc)[4][4],
                                           int lane, int c0)
{
  const int lr  = lane & 15;
  const int lk8 = (lane >> 4) * 8;
  #pragma unroll
  for(int kc = 0; kc < 8; ++kc){
    bf16x8 af[4], bfr[4];
    #pragma unroll
    for(int fr = 0; fr < 4; ++fr)
      af[fr] = *(const bf16x8*)(As + swzA(fr*16 + lr, kc*64 + lk8*2));
    #pragma unroll
    for(int fc = 0; fc < 4; ++fc)
      bfr[fc] = *(const bf16x8*)(wb + (size_t)(c0 + fc*16 + lr)*256 + kc*32 + lk8);
    #pragma unroll
    for(int fr = 0; fr < 4; ++fr)
      #pragma unroll
      for(int fc = 0; fc < 4; ++fc)
        acc[fr][fc] = __builtin_amdgcn_mfma_f32_16x16x32_bf16(af[fr], bfr[fc], acc[fr][fc], 0, 0, 0);
  }
}

// LDS-staged GEMM (k_in_proj / k_out only, v2-validated)
template<int KCH>
__device__ __forceinline__ void gemm_64x256(const unsigned short* __restrict__ wb,
                                            char* As, char* Bs,
                                            f32x4 (&acc)[4][4], int tid)
{
  const int lane = tid & 63;
  const int c0   = (tid >> 6) * 64;
  const int lr   = lane & 15;
  const int lk16 = (lane >> 4) * 16;
  #pragma unroll
  for(int kc = 0; kc < KCH; ++kc){
    __syncthreads();
    {
      const unsigned short* src = wb + (size_t)tid * (KCH*64) + kc*64;
      #pragma unroll
      for(int i = 0; i < 8; ++i){
        short8 v = *(const short8*)(src + i*8);
        *(short8*)(Bs + swzB(tid, i*16)) = v;
      }
    }
    __syncthreads();
    #pragma unroll
    for(int t2 = 0; t2 < 2; ++t2){
      bf16x8 af[4], bfr[4];
      #pragma unroll
      for(int fr = 0; fr < 4; ++fr)
        af[fr] = *(const bf16x8*)(As + swzA(fr*16 + lr, kc*128 + t2*64 + lk16));
      #pragma unroll
      for(int fc = 0; fc < 4; ++fc)
        bfr[fc] = *(const bf16x8*)(Bs + swzB(c0 + fc*16 + lr, t2*64 + lk16));
      #pragma unroll
      for(int fr = 0; fr < 4; ++fr)
        #pragma unroll
        for(int fc = 0; fc < 4; ++fc)
          acc[fr][fc] = __builtin_amdgcn_mfma_f32_16x16x32_bf16(af[fr], bfr[fc], acc[fr][fc], 0, 0, 0);
    }
  }
}

// ---------------- prep kernels ----------------
__global__ void k_cvt(const float* __restrict__ s, unsigned short* __restrict__ d, int n){
  int i = blockIdx.x*256 + threadIdx.x;
  if(i < n) d[i] = f2bf(s[i]);
}
__global__ void k_cvt_inw(const float* __restrict__ w, unsigned short* __restrict__ d){
  int i = blockIdx.x*256 + threadIdx.x;
  int n = i >> 7, f = i & 127;
  d[i] = (f < 96) ? f2bf(w[n*96 + f]) : (unsigned short)0;
}
__global__ void k_spT(const float* __restrict__ spw, unsigned short* __restrict__ d){
  int l = blockIdx.y;
  int i = blockIdx.x*256 + threadIdx.x;
  int dd = i >> 8, ss = i & 255;
  d[l*65536 + i] = f2bf(spw[l*65536 + ss*256 + dd]);
}
__global__ void k_decay(const float* __restrict__ A_log, float* __restrict__ decay){
  int l = blockIdx.x, d = threadIdx.x;
  const float* row = A_log + ((size_t)l*256 + d)*256;
  float acc = 0.f;
  for(int s = 0; s < 256; ++s) acc += expf(row[s]);
  decay[l*256 + d] = expf(-acc * (1.f/256.f));
}

// ---------------- h = gelu(LN(x @ in_w^T + in_b)) -> bf16 (v2 verbatim) ----------------
__global__ __launch_bounds__(256) void k_in_proj(
    const float* __restrict__ x_g,
    const unsigned short* __restrict__ in_wb,
    const float* __restrict__ in_b,
    const float* __restrict__ ln_gv, const float* __restrict__ ln_bv,
    unsigned short* __restrict__ h_g)
{
  __shared__ char smem[65536];
  char* As = smem; char* Bs = smem + 32768;
  const int tid = threadIdx.x;
  const int m0 = blockIdx.x * 64;
  const int lane = tid & 63, c0w = (tid>>6)*64, lr = lane & 15, rb = (lane>>4)*4;
  {
    const int r = tid >> 2, cq = tid & 3;
    const float* src = x_g + (size_t)(m0 + r)*FIN + cq*24;
    unsigned short tmp[24] __attribute__((aligned(16)));
    #pragma unroll
    for(int i = 0; i < 6; ++i){
      float4 v = *(const float4*)(src + i*4);
      tmp[4*i]=f2bf(v.x); tmp[4*i+1]=f2bf(v.y); tmp[4*i+2]=f2bf(v.z); tmp[4*i+3]=f2bf(v.w);
    }
    #pragma unroll
    for(int i = 0; i < 3; ++i)
      *(short8*)(As + swzA(r, cq*48 + i*16)) = *(const short8*)(tmp + i*8);
    if(cq == 3){
      short8 z8 = {0,0,0,0,0,0,0,0};
      #pragma unroll
      for(int i = 0; i < 4; ++i)
        *(short8*)(As + swzA(r, 192 + i*16)) = z8;
    }
  }
  f32x4 acc[4][4]; zero_acc(acc);
  gemm_64x256<2>(in_wb, As, Bs, acc, tid);
  __syncthreads();
  #pragma unroll
  for(int fc = 0; fc < 4; ++fc){
    const int col = c0w + fc*16 + lr;
    const float bb = in_b[col];
    #pragma unroll
    for(int fr = 0; fr < 4; ++fr)
      #pragma unroll
      for(int rg = 0; rg < 4; ++rg){
        const int row = fr*16 + rb + rg;
        *(float*)(smem + (((unsigned)(row*1024 + col*4)) ^ ((row&7)<<4))) = acc[fr][fc][rg] + bb;
      }
  }
  __syncthreads();
  {
    const int r = tid >> 2, c0 = (tid & 3) * 64;
    float vals[64]; float sm = 0.f, sq = 0.f;
    #pragma unroll
    for(int i = 0; i < 16; ++i){
      float4 v = *(const float4*)(smem + (((unsigned)(r*1024 + (c0 + i*4)*4)) ^ ((r&7)<<4)));
      vals[4*i]=v.x; vals[4*i+1]=v.y; vals[4*i+2]=v.z; vals[4*i+3]=v.w;
    }
    #pragma unroll
    for(int i = 0; i < 64; ++i){ sm += vals[i]; sq += vals[i]*vals[i]; }
    sm += __shfl_xor(sm, 1); sm += __shfl_xor(sm, 2);
    sq += __shfl_xor(sq, 1); sq += __shfl_xor(sq, 2);
    const float mu = sm * (1.f/256.f);
    const float rstd = rsqrtf(sq * (1.f/256.f) - mu*mu + 1e-5f);
    unsigned short* dst = h_g + (size_t)(m0 + r)*DMODEL + c0;
    #pragma unroll
    for(int i = 0; i < 8; ++i){
      short8 o;
      #pragma unroll
      for(int j = 0; j < 8; ++j){
        const int c = c0 + i*8 + j;
        o[j] = (short)f2bf(gelu_f((vals[i*8+j]-mu)*rstd*ln_gv[c] + ln_bv[c]));
      }
      *(short8*)(dst + i*8) = o;
    }
  }
}

// ---------------- shared phase: LN(h)->z; xg=silu(z@gate^T+b); s=xg@sp^T+b -> As ----------------
template<bool SAVE_XG>
__device__ __forceinline__ void compute_s_tile(
    const unsigned short* __restrict__ h_g, int m0, char* As,
    const unsigned short* __restrict__ gate_wb,
    const unsigned short* __restrict__ sp_wb,
    const float* __restrict__ ln_gv, const float* __restrict__ ln_bv,
    const float* __restrict__ gate_bv, const float* __restrict__ sp_bv,
    int tid, f32x4 (&xg_reg)[4][4])
{
  const int lane = tid & 63, c0w = (tid>>6)*64, lr = lane & 15, rb = (lane>>4)*4;
  // LN(h) -> z bf16 in As (v2 verbatim)
  {
    const int r = tid >> 2, c0 = (tid & 3) * 64;
    const unsigned short* src = h_g + (size_t)(m0 + r)*DMODEL + c0;
    short8 hv[8];
    #pragma unroll
    for(int i = 0; i < 8; ++i) hv[i] = *(const short8*)(src + i*8);
    float sm = 0.f, sq = 0.f;
    #pragma unroll
    for(int i = 0; i < 8; ++i)
      #pragma unroll
      for(int j = 0; j < 8; ++j){
        float v = bf2f((unsigned short)hv[i][j]); sm += v; sq += v*v;
      }
    sm += __shfl_xor(sm, 1); sm += __shfl_xor(sm, 2);
    sq += __shfl_xor(sq, 1); sq += __shfl_xor(sq, 2);
    const float mu = sm * (1.f/256.f);
    const float rstd = rsqrtf(sq * (1.f/256.f) - mu*mu + 1e-5f);
    #pragma unroll
    for(int i = 0; i < 8; ++i){
      short8 z;
      #pragma unroll
      for(int j = 0; j < 8; ++j){
        const int c = c0 + i*8 + j;
        z[j] = (short)f2bf((bf2f((unsigned short)hv[i][j])-mu)*rstd*ln_gv[c] + ln_bv[c]);
      }
      *(short8*)(As + swzA(r, c0*2 + i*16)) = z;
    }
  }
  __syncthreads();
  f32x4 acc[4][4]; zero_acc(acc);
  gemm_waveB(gate_wb, As, acc, lane, c0w);
  __syncthreads();
  // xg = silu(acc+gb) -> As (+ fp32 regs if SAVE_XG)
  #pragma unroll
  for(int fc = 0; fc < 4; ++fc){
    const int col = c0w + fc*16 + lr;
    const float gb = gate_bv[col];
    #pragma unroll
    for(int fr = 0; fr < 4; ++fr)
      #pragma unroll
      for(int rg = 0; rg < 4; ++rg){
        const float v = silu_f(acc[fr][fc][rg] + gb);
        if constexpr (SAVE_XG) xg_reg[fr][fc][rg] = v;
        *(unsigned short*)(As + swzA(fr*16 + rb + rg, col*2)) = f2bf(v);
      }
  }
  __syncthreads();
  zero_acc(acc);
  gemm_waveB(sp_wb, As, acc, lane, c0w);
  __syncthreads();
  // s = acc + sp_b -> As
  #pragma unroll
  for(int fc = 0; fc < 4; ++fc){
    const int col = c0w + fc*16 + lr;
    const float sb = sp_bv[col];
    #pragma unroll
    for(int fr = 0; fr < 4; ++fr)
      #pragma unroll
      for(int rg = 0; rg < 4; ++rg)
        *(unsigned short*)(As + swzA(fr*16 + rb + rg, col*2)) = f2bf(acc[fr][fc][rg] + sb);
  }
  __syncthreads();
}

// ---------------- k_seed: seed[b+1] = sum_j dc^(63-j) * s_tile(b)[j] ----------------
__global__ __launch_bounds__(256) void k_seed(
    const unsigned short* __restrict__ h_g,
    const unsigned short* __restrict__ gate_wb,
    const unsigned short* __restrict__ sp_wb,
    const float* __restrict__ ln_gv, const float* __restrict__ ln_bv,
    const float* __restrict__ gate_bv, const float* __restrict__ sp_bv,
    const float* __restrict__ decay_v,
    float* __restrict__ seed_buf)
{
  __shared__ char As[32768];
  const int b = blockIdx.x;
  if((b & 7) == 7) return;        // next tile starts a new sequence
  const int tid = threadIdx.x;
  f32x4 xg_dummy[4][4];
  compute_s_tile<false>(h_g, b*64, As, gate_wb, sp_wb, ln_gv, ln_bv, gate_bv, sp_bv, tid, xg_dummy);
  const float dc = decay_v[tid];
  float sd = 0.f;
  #pragma unroll 4
  for(int j = 0; j < 64; ++j)
    sd = sd*dc + bf2f(*(const unsigned short*)(As + swzA(j, tid*2)));
  seed_buf[(size_t)(b+1)*256 + tid] = sd;
}

// ---------------- k_tile: s; scan(seed); spT; y=+D*xg; op; h-RMW ----------------
__global__ __launch_bounds__(256) void k_tile(
    unsigned short* __restrict__ h_g,
    const unsigned short* __restrict__ gate_wb,
    const unsigned short* __restrict__ sp_wb,
    const unsigned short* __restrict__ spT_wb,
    const unsigned short* __restrict__ op_wb,
    const float* __restrict__ ln_gv, const float* __restrict__ ln_bv,
    const float* __restrict__ gate_bv, const float* __restrict__ sp_bv,
    const float* __restrict__ decay_v, const float* __restrict__ D_v,
    const float* __restrict__ op_bv,
    const float* __restrict__ seed_buf,
    float* __restrict__ state_buf, const int layer)
{
  __shared__ char As[32768];
  const int tid = threadIdx.x;
  const int b = blockIdx.x;
  const int m0 = b * 64;
  const int n = m0 >> 9;
  const int kb = b & 7;
  const int lane = tid & 63, c0w = (tid>>6)*64, lr = lane & 15, rb = (lane>>4)*4;
  f32x4 xg_reg[4][4];
  compute_s_tile<true>(h_g, m0, As, gate_wb, sp_wb, ln_gv, ln_bv, gate_bv, sp_bv, tid, xg_reg);
  // scan (thread = channel), seeded
  const float dc = decay_v[tid];
  float st = (kb == 0) ? ((layer > 0) ? state_buf[n*256 + tid] : 0.f)
                       : seed_buf[(size_t)b*256 + tid];
  #pragma unroll 4
  for(int j = 0; j < 64; ++j){
    const unsigned a = swzA(j, tid*2);
    st = st*dc + bf2f(*(const unsigned short*)(As + a));
    *(unsigned short*)(As + a) = f2bf(st);
  }
  if(kb == 7) state_buf[n*256 + tid] = st;
  __syncthreads();
  f32x4 acc[4][4]; zero_acc(acc);
  gemm_waveB(spT_wb, As, acc, lane, c0w);   // y1 = states@sp_w
  __syncthreads();
  // y = acc + D*xg (fp32) -> As
  #pragma unroll
  for(int fc = 0; fc < 4; ++fc){
    const int col = c0w + fc*16 + lr;
    const float Dv = D_v[col];
    #pragma unroll
    for(int fr = 0; fr < 4; ++fr)
      #pragma unroll
      for(int rg = 0; rg < 4; ++rg)
        *(unsigned short*)(As + swzA(fr*16 + rb + rg, col*2)) =
            f2bf(acc[fr][fc][rg] + Dv*xg_reg[fr][fc][rg]);
  }
  __syncthreads();
  zero_acc(acc);
  gemm_waveB(op_wb, As, acc, lane, c0w);    // @op^T
  __syncthreads();
  // acc + op_b -> As bf16
  #pragma unroll
  for(int fc = 0; fc < 4; ++fc){
    const int col = c0w + fc*16 + lr;
    const float ob = op_bv[col];
    #pragma unroll
    for(int fr = 0; fr < 4; ++fr)
      #pragma unroll
      for(int rg = 0; rg < 4; ++rg)
        *(unsigned short*)(As + swzA(fr*16 + rb + rg, col*2)) = f2bf(acc[fr][fc][rg] + ob);
  }
  __syncthreads();
  // h += (y@op^T + op_b), coalesced RMW (v2 verbatim)
  {
    char* dst = (char*)(h_g + (size_t)m0*DMODEL);
    #pragma unroll
    for(int i = 0; i < 8; ++i){
      const unsigned flat = (unsigned)(i*4096 + tid*16);
      const unsigned row = flat >> 9;
      short8 a = *(const short8*)(As + (flat ^ ((row & 7u) << 4)));
      short8 hv = *(const short8*)(dst + flat);
      short8 o;
      #pragma unroll
      for(int j = 0; j < 8; ++j)
        o[j] = (short)f2bf(bf2f((unsigned short)a[j]) + bf2f((unsigned short)hv[j]));
      *(short8*)(dst + flat) = o;
    }
  }
}

// ---------------- out = gelu(LN(h[:,511,:] @ out_w^T + out_b)) (v2 verbatim) ----------------
__global__ __launch_bounds__(256) void k_out(
    const unsigned short* __restrict__ h_g,
    const unsigned short* __restrict__ out_wb,
    const float* __restrict__ out_bv,
    const float* __restrict__ ln_gv, const float* __restrict__ ln_bv,
    float* __restrict__ out_g)
{
  __shared__ char smem[65536];
  char* As = smem; char* Bs = smem + 32768;
  const int tid = threadIdx.x;
  const int r0 = blockIdx.x * 64;
  const int lane = tid & 63, c0w = (tid>>6)*64, lr = lane & 15, rb = (lane>>4)*4;
  {
    const int r = tid >> 2, c0 = (tid & 3) * 64;
    const unsigned short* src = h_g + ((size_t)(r0 + r)*KSEQ + (KSEQ-1))*DMODEL + c0;
    #pragma unroll
    for(int i = 0; i < 8; ++i){
      short8 v = *(const short8*)(src + i*8);
      *(short8*)(As + swzA(r, c0*2 + i*16)) = v;
    }
  }
  f32x4 acc[4][4]; zero_acc(acc);
  gemm_64x256<4>(out_wb, As, Bs, acc, tid);
  __syncthreads();
  #pragma unroll
  for(int fc = 0; fc < 4; ++fc){
    const int col = c0w + fc*16 + lr;
    const float bb = out_bv[col];
    #pragma unroll
    for(int fr = 0; fr < 4; ++fr)
      #pragma unroll
      for(int rg = 0; rg < 4; ++rg){
        const int row = fr*16 + rb + rg;
        *(float*)(smem + (((unsigned)(row*1024 + col*4)) ^ ((row&7)<<4))) = acc[fr][fc][rg] + bb;
      }
  }
  __syncthreads();
  {
    const int r = tid >> 2, c0 = (tid & 3) * 64;
    float vals[64]; float sm = 0.f, sq = 0.f;
    #pragma unroll
    for(int i = 0; i < 16; ++i){
      float4 v = *(const float4*)(smem + (((unsigned)(r*1024 + (c0 + i*4)*4)) ^ ((r&7)<<4)));
      vals[4*i]=v.x; vals[4*i+1]=v.y; vals[4*i+2]=v.z; vals[4*i+3]=v.w;
    }
    #pragma unroll
    for(int i = 0; i < 64; ++i){ sm += vals[i]; sq += vals[i]*vals[i]; }
    sm += __shfl_xor(sm, 1); sm += __shfl_xor(sm, 2);
    sq += __shfl_xor(sq, 1); sq += __shfl_xor(sq, 2);
    const float mu = sm * (1.f/256.f);
    const float rstd = rsqrtf(sq * (1.f/256.f) - mu*mu + 1e-5f);
    float* dst = out_g + (size_t)(r0 + r)*DMODEL + c0;
    #pragma unroll
    for(int i = 0; i < 16; ++i){
      float4 o;
      o.x = gelu_f((vals[4*i+0]-mu)*rstd*ln_gv[c0+i*4+0] + ln_bv[c0+i*4+0]);
      o.y = gelu_f((vals[4*i+1]-mu)*rstd*ln_gv[c0+i*4+1] + ln_bv[c0+i*4+1]);
      o.z = gelu_f((vals[4*i+2]-mu)*rstd*ln_gv[c0+i*4+2] + ln_bv[c0+i*4+2]);
      o.w = gelu_f((vals[4*i+3]-mu)*rstd*ln_gv[c0+i*4+3] + ln_bv[c0+i*4+3]);
      *(float4*)(dst + i*4) = o;
    }
  }
}

extern "C" void kernel_launch(void* const* d_in, const int* in_sizes, int n_in,
                              void* d_out, int out_size, void* d_ws, size_t ws_size,
                              hipStream_t stream) {
  (void)in_sizes; (void)n_in; (void)out_size; (void)ws_size;
  const float* x        = (const float*)d_in[0];
  const float* in_w     = (const float*)d_in[1];
  const float* in_b     = (const float*)d_in[2];
  const float* in_ln_g  = (const float*)d_in[3];
  const float* in_ln_b  = (const float*)d_in[4];
  const float* ln_g     = (const float*)d_in[5];
  const float* ln_b     = (const float*)d_in[6];
  const float* gate_w   = (const float*)d_in[7];
  const float* gate_b   = (const float*)d_in[8];
  const float* sp_w     = (const float*)d_in[9];
  const float* sp_b     = (const float*)d_in[10];
  const float* op_w     = (const float*)d_in[11];
  const float* op_b     = (const float*)d_in[12];
  const float* A_log    = (const float*)d_in[13];
  const float* Dp       = (const float*)d_in[14];
  const float* out_w    = (const float*)d_in[15];
  const float* out_b    = (const float*)d_in[16];
  const float* out_ln_g = (const float*)d_in[17];
  const float* out_ln_b = (const float*)d_in[18];

  char* ws = (char*)d_ws;
  // ~134 MiB workspace (v2-proven budget + 4MiB seeds)
  unsigned short* h_g       = (unsigned short*)(ws + 0);           // 128 MiB
  float*          seed_buf  = (float*)(ws + 134217728);            // 4 MiB
  float*          state_buf = (float*)(ws + 138412032);            // 512 KiB
  float*          decay     = (float*)(ws + 138936320);            // 2 KiB
  unsigned short* wbase     = (unsigned short*)(ws + 138938368);   // ~1.2 MiB
  unsigned short* in_wb  = wbase;               // 32768
  unsigned short* gate_wb= in_wb  + 32768;      // 2*65536
  unsigned short* sp_wb  = gate_wb+ 131072;
  unsigned short* sp_wTb = sp_wb  + 131072;
  unsigned short* op_wb  = sp_wTb + 131072;
  unsigned short* out_wb = op_wb  + 131072;     // 65536

  // prep
  k_cvt_inw<<<128, 256, 0, stream>>>(in_w, in_wb);
  k_cvt<<<512, 256, 0, stream>>>(gate_w, gate_wb, 131072);
  k_cvt<<<512, 256, 0, stream>>>(sp_w,   sp_wb,   131072);
  k_cvt<<<512, 256, 0, stream>>>(op_w,   op_wb,   131072);
  k_cvt<<<256, 256, 0, stream>>>(out_w,  out_wb,  65536);
  k_spT<<<dim3(256,2), 256, 0, stream>>>(sp_w, sp_wTb);
  k_decay<<<2, 256, 0, stream>>>(A_log, decay);

  // pipeline
  k_in_proj<<<MTOT/64, 256, 0, stream>>>(x, in_wb, in_b, in_ln_g, in_ln_b, h_g);
  for(int l = 0; l < 2; ++l){
    k_seed<<<MTOT/64, 256, 0, stream>>>(h_g, gate_wb + l*65536, sp_wb + l*65536,
        ln_g + l*256, ln_b + l*256, gate_b + l*256, sp_b + l*256,
        decay + l*256, seed_buf);
    k_tile<<<MTOT/64, 256, 0, stream>>>(h_g,
        gate_wb + l*65536, sp_wb + l*65536, sp_wTb + l*65536, op_wb + l*65536,
        ln_g + l*256, ln_b + l*256, gate_b + l*256, sp_b + l*256,
        decay + l*256, Dp + l*256, op_b + l*256,
        seed_buf, state_buf, l);
  }
  k_out<<<NSEQ/64, 256, 0, stream>>>(h_g, out_wb, out_b, out_ln_g, out_ln_b, (float*)d_out);
}

// Round 5
// 1334.333 us; speedup vs baseline: 1.6999x; 1.3472x over previous
//
#include <hip/hip_runtime.h>
#include <hip/hip_bf16.h>

// MambaEncoder on MI355X — v5: one kernel per layer (block = sequence, 8 serial
// tiles, EXACT register-carried scan; no seed pass). Per tile: 7 barrier-phases,
// two 32KB LDS buffers, barrier-free waveB GEMMs with explicit B-prefetch,
// v_cvt_pk_bf16_f32 epilogues, chunked scan.
//   k_in_proj: h = gelu(LN(x @ in_w^T + in_b))  (v2-proven structure)
//   k_layer x2: per tile: LN->As | gate(As)->xg->Ss | sp(Ss)->s->As | scan(As)
//               | spT(As) | y=acc+D*xg(Ss)->As | op(As)->Ss | h += Ss
//   k_out: out = gelu(LN(h[:,511,:] @ out_w^T + out_b))
// ws ~133.7 MiB (v2-proven budget): h bf16 128Mi + state/decay/weights.

typedef __attribute__((ext_vector_type(8))) __bf16 bf16x8;
typedef __attribute__((ext_vector_type(8))) short short8;
typedef __attribute__((ext_vector_type(4))) float f32x4;

#define NSEQ 512
#define KSEQ 512
#define FIN 96
#define DMODEL 256
#define MTOT (NSEQ*KSEQ)

__device__ __forceinline__ unsigned short f2bf(float f){
  union { float f; unsigned u; } v; v.f = f;
  unsigned r = (v.u + 0x7FFFu + ((v.u >> 16) & 1u)) >> 16;
  return (unsigned short)r;
}
__device__ __forceinline__ float bf2f(unsigned short b){
  union { unsigned u; float f; } v; v.u = ((unsigned)b) << 16; return v.f;
}
// packed 2xf32 -> 2xbf16 (RNE, matches f2bf), 1 VALU inst
__device__ __forceinline__ unsigned pk_bf16(float lo, float hi){
  unsigned r;
  asm("v_cvt_pk_bf16_f32 %0, %1, %2" : "=v"(r) : "v"(lo), "v"(hi));
  return r;
}
__device__ __forceinline__ float gelu_f(float x){
  return 0.5f * x * (1.0f + erff(x * 0.70710678118654752440f));
}
__device__ __forceinline__ float silu_f(float x){
  return x / (1.0f + __expf(-x));
}
__device__ __forceinline__ unsigned swzA(int row, int kbyte){   // [64][256] bf16, 512B stride
  return ((unsigned)(row*512 + kbyte)) ^ (unsigned)((row & 7) << 4);
}
__device__ __forceinline__ unsigned swzB(int n, int kbyte){     // [256][64] bf16
  return ((unsigned)(n*128 + kbyte)) ^ (unsigned)((n & 7) << 4);
}

__device__ __forceinline__ void zero_acc(f32x4 (&acc)[4][4]){
  #pragma unroll
  for(int a=0;a<4;++a)
    #pragma unroll
    for(int b=0;b<4;++b)
      acc[a][b] = (f32x4){0.f,0.f,0.f,0.f};
}

// per-wave GEMM K=256: acc += A(64x256 bf16 LDS, swzA) @ W[256][256]^T.
// B direct from global (L2-hot) with explicit next-chunk prefetch.
__device__ __forceinline__ void gemm_waveB(const unsigned short* __restrict__ wb,
                                           const char* As, f32x4 (&acc)[4][4],
                                           int lane, int c0)
{
  const int lr  = lane & 15;
  const int lk8 = (lane >> 4) * 8;
  const unsigned short* bp = wb + (size_t)(c0 + lr)*256 + lk8;   // + fc*4096 + kc*32
  bf16x8 bcur[4], bnxt[4];
  #pragma unroll
  for(int fc = 0; fc < 4; ++fc) bcur[fc] = *(const bf16x8*)(bp + fc*4096);
  #pragma unroll
  for(int kc = 0; kc < 8; ++kc){
    if(kc < 7){
      #pragma unroll
      for(int fc = 0; fc < 4; ++fc) bnxt[fc] = *(const bf16x8*)(bp + fc*4096 + (kc+1)*32);
    }
    bf16x8 af[4];
    #pragma unroll
    for(int fr = 0; fr < 4; ++fr)
      af[fr] = *(const bf16x8*)(As + swzA(fr*16 + lr, kc*64 + lk8*2));
    #pragma unroll
    for(int fr = 0; fr < 4; ++fr)
      #pragma unroll
      for(int fc = 0; fc < 4; ++fc)
        acc[fr][fc] = __builtin_amdgcn_mfma_f32_16x16x32_bf16(af[fr], bcur[fc], acc[fr][fc], 0, 0, 0);
    #pragma unroll
    for(int fc = 0; fc < 4; ++fc) bcur[fc] = bnxt[fc];
  }
}

// LDS-staged GEMM (k_in_proj / k_out only, proven)
template<int KCH>
__device__ __forceinline__ void gemm_64x256(const unsigned short* __restrict__ wb,
                                            char* As, char* Bs,
                                            f32x4 (&acc)[4][4], int tid)
{
  const int lane = tid & 63;
  const int c0   = (tid >> 6) * 64;
  const int lr   = lane & 15;
  const int lk16 = (lane >> 4) * 16;
  #pragma unroll
  for(int kc = 0; kc < KCH; ++kc){
    __syncthreads();
    {
      const unsigned short* src = wb + (size_t)tid * (KCH*64) + kc*64;
      #pragma unroll
      for(int i = 0; i < 8; ++i){
        short8 v = *(const short8*)(src + i*8);
        *(short8*)(Bs + swzB(tid, i*16)) = v;
      }
    }
    __syncthreads();
    #pragma unroll
    for(int t2 = 0; t2 < 2; ++t2){
      bf16x8 af[4], bfr[4];
      #pragma unroll
      for(int fr = 0; fr < 4; ++fr)
        af[fr] = *(const bf16x8*)(As + swzA(fr*16 + lr, kc*128 + t2*64 + lk16));
      #pragma unroll
      for(int fc = 0; fc < 4; ++fc)
        bfr[fc] = *(const bf16x8*)(Bs + swzB(c0 + fc*16 + lr, t2*64 + lk16));
      #pragma unroll
      for(int fr = 0; fr < 4; ++fr)
        #pragma unroll
        for(int fc = 0; fc < 4; ++fc)
          acc[fr][fc] = __builtin_amdgcn_mfma_f32_16x16x32_bf16(af[fr], bfr[fc], acc[fr][fc], 0, 0, 0);
    }
  }
}

// ---------------- prep kernels ----------------
__global__ void k_cvt(const float* __restrict__ s, unsigned short* __restrict__ d, int n){
  int i = blockIdx.x*256 + threadIdx.x;
  if(i < n) d[i] = f2bf(s[i]);
}
__global__ void k_cvt_inw(const float* __restrict__ w, unsigned short* __restrict__ d){
  int i = blockIdx.x*256 + threadIdx.x;
  int n = i >> 7, f = i & 127;
  d[i] = (f < 96) ? f2bf(w[n*96 + f]) : (unsigned short)0;
}
__global__ void k_spT(const float* __restrict__ spw, unsigned short* __restrict__ d){
  int l = blockIdx.y;
  int i = blockIdx.x*256 + threadIdx.x;
  int dd = i >> 8, ss = i & 255;
  d[l*65536 + i] = f2bf(spw[l*65536 + ss*256 + dd]);
}
__global__ void k_decay(const float* __restrict__ A_log, float* __restrict__ decay){
  int l = blockIdx.x, d = threadIdx.x;
  const float* row = A_log + ((size_t)l*256 + d)*256;
  float acc = 0.f;
  for(int s = 0; s < 256; ++s) acc += expf(row[s]);
  decay[l*256 + d] = expf(-acc * (1.f/256.f));
}

// ---------------- h = gelu(LN(x @ in_w^T + in_b)) -> bf16 (proven) ----------------
__global__ __launch_bounds__(256) void k_in_proj(
    const float* __restrict__ x_g,
    const unsigned short* __restrict__ in_wb,
    const float* __restrict__ in_b,
    const float* __restrict__ ln_gv, const float* __restrict__ ln_bv,
    unsigned short* __restrict__ h_g)
{
  __shared__ char smem[65536];
  char* As = smem; char* Bs = smem + 32768;
  const int tid = threadIdx.x;
  const int m0 = blockIdx.x * 64;
  const int lane = tid & 63, c0w = (tid>>6)*64, lr = lane & 15, rb = (lane>>4)*4;
  {
    const int r = tid >> 2, cq = tid & 3;
    const float* src = x_g + (size_t)(m0 + r)*FIN + cq*24;
    unsigned short tmp[24] __attribute__((aligned(16)));
    #pragma unroll
    for(int i = 0; i < 6; ++i){
      float4 v = *(const float4*)(src + i*4);
      tmp[4*i]=f2bf(v.x); tmp[4*i+1]=f2bf(v.y); tmp[4*i+2]=f2bf(v.z); tmp[4*i+3]=f2bf(v.w);
    }
    #pragma unroll
    for(int i = 0; i < 3; ++i)
      *(short8*)(As + swzA(r, cq*48 + i*16)) = *(const short8*)(tmp + i*8);
    if(cq == 3){
      short8 z8 = {0,0,0,0,0,0,0,0};
      #pragma unroll
      for(int i = 0; i < 4; ++i)
        *(short8*)(As + swzA(r, 192 + i*16)) = z8;
    }
  }
  f32x4 acc[4][4]; zero_acc(acc);
  gemm_64x256<2>(in_wb, As, Bs, acc, tid);
  __syncthreads();
  #pragma unroll
  for(int fc = 0; fc < 4; ++fc){
    const int col = c0w + fc*16 + lr;
    const float bb = in_b[col];
    #pragma unroll
    for(int fr = 0; fr < 4; ++fr)
      #pragma unroll
      for(int rg = 0; rg < 4; ++rg){
        const int row = fr*16 + rb + rg;
        *(float*)(smem + (((unsigned)(row*1024 + col*4)) ^ ((row&7)<<4))) = acc[fr][fc][rg] + bb;
      }
  }
  __syncthreads();
  {
    const int r = tid >> 2, c0 = (tid & 3) * 64;
    float vals[64]; float sm = 0.f, sq = 0.f;
    #pragma unroll
    for(int i = 0; i < 16; ++i){
      float4 v = *(const float4*)(smem + (((unsigned)(r*1024 + (c0 + i*4)*4)) ^ ((r&7)<<4)));
      vals[4*i]=v.x; vals[4*i+1]=v.y; vals[4*i+2]=v.z; vals[4*i+3]=v.w;
    }
    #pragma unroll
    for(int i = 0; i < 64; ++i){ sm += vals[i]; sq += vals[i]*vals[i]; }
    sm += __shfl_xor(sm, 1); sm += __shfl_xor(sm, 2);
    sq += __shfl_xor(sq, 1); sq += __shfl_xor(sq, 2);
    const float mu = sm * (1.f/256.f);
    const float rstd = rsqrtf(sq * (1.f/256.f) - mu*mu + 1e-5f);
    unsigned short* dst = h_g + (size_t)(m0 + r)*DMODEL + c0;
    #pragma unroll
    for(int i = 0; i < 8; ++i){
      float g[8];
      #pragma unroll
      for(int j = 0; j < 8; ++j){
        const int c = c0 + i*8 + j;
        g[j] = gelu_f((vals[i*8+j]-mu)*rstd*ln_gv[c] + ln_bv[c]);
      }
      uint4 o;
      o.x = pk_bf16(g[0],g[1]); o.y = pk_bf16(g[2],g[3]);
      o.z = pk_bf16(g[4],g[5]); o.w = pk_bf16(g[6],g[7]);
      *(uint4*)(dst + i*8) = o;
    }
  }
}

// ---------------- full layer: block = sequence, 8 serial tiles, exact scan ----------------
__global__ __launch_bounds__(256,2) void k_layer(
    unsigned short* __restrict__ h_g,
    const unsigned short* __restrict__ gate_wb,
    const unsigned short* __restrict__ sp_wb,
    const unsigned short* __restrict__ spT_wb,
    const unsigned short* __restrict__ op_wb,
    const float* __restrict__ ln_gv, const float* __restrict__ ln_bv,
    const float* __restrict__ gate_bv, const float* __restrict__ sp_bv,
    const float* __restrict__ decay_v, const float* __restrict__ D_v,
    const float* __restrict__ op_bv,
    float* __restrict__ state_buf, const int layer)
{
  __shared__ char As[32768];
  __shared__ char Ss[32768];
  const int tid = threadIdx.x;
  const int n = blockIdx.x;
  const int lane = tid & 63, c0w = (tid>>6)*64, lr = lane & 15, rb = (lane>>4)*4;
  const float dc = decay_v[tid];
  float st = (layer > 0) ? state_buf[n*256 + tid] : 0.f;

  #pragma unroll 1
  for(int kb = 0; kb < 8; ++kb){
    const int m0 = n*KSEQ + kb*64;
    // ---- Phase A: LN(h) -> z bf16 in As ----
    {
      const int r = tid >> 2, c0 = (tid & 3) * 64;
      const unsigned short* src = h_g + (size_t)(m0 + r)*DMODEL + c0;
      short8 hv[8];
      #pragma unroll
      for(int i = 0; i < 8; ++i) hv[i] = *(const short8*)(src + i*8);
      float sm = 0.f, sq = 0.f;
      #pragma unroll
      for(int i = 0; i < 8; ++i)
        #pragma unroll
        for(int j = 0; j < 8; ++j){
          float v = bf2f((unsigned short)hv[i][j]); sm += v; sq += v*v;
        }
      sm += __shfl_xor(sm, 1); sm += __shfl_xor(sm, 2);
      sq += __shfl_xor(sq, 1); sq += __shfl_xor(sq, 2);
      const float mu = sm * (1.f/256.f);
      const float rstd = rsqrtf(sq * (1.f/256.f) - mu*mu + 1e-5f);
      #pragma unroll
      for(int i = 0; i < 8; ++i){
        float z[8];
        #pragma unroll
        for(int j = 0; j < 8; ++j){
          const int c = c0 + i*8 + j;
          z[j] = (bf2f((unsigned short)hv[i][j])-mu)*rstd*ln_gv[c] + ln_bv[c];
        }
        uint4 zz;
        zz.x = pk_bf16(z[0],z[1]); zz.y = pk_bf16(z[2],z[3]);
        zz.z = pk_bf16(z[4],z[5]); zz.w = pk_bf16(z[6],z[7]);
        *(uint4*)(As + swzA(r, c0*2 + i*16)) = zz;
      }
    }
    __syncthreads();                                   // S1
    f32x4 acc[4][4]; zero_acc(acc);
    gemm_waveB(gate_wb, As, acc, lane, c0w);
    // xg = silu(acc+gb) -> Ss (persists until y-epilogue)
    #pragma unroll
    for(int fc = 0; fc < 4; ++fc){
      const int col = c0w + fc*16 + lr;
      const float gb = gate_bv[col];
      #pragma unroll
      for(int fr = 0; fr < 4; ++fr){
        const int row = fr*16 + rb;
        float v0 = silu_f(acc[fr][fc][0] + gb), v1 = silu_f(acc[fr][fc][1] + gb);
        float v2 = silu_f(acc[fr][fc][2] + gb), v3 = silu_f(acc[fr][fc][3] + gb);
        unsigned p0 = pk_bf16(v0, v1), p1 = pk_bf16(v2, v3);
        *(unsigned short*)(Ss + swzA(row+0, col*2)) = (unsigned short)p0;
        *(unsigned short*)(Ss + swzA(row+1, col*2)) = (unsigned short)(p0 >> 16);
        *(unsigned short*)(Ss + swzA(row+2, col*2)) = (unsigned short)p1;
        *(unsigned short*)(Ss + swzA(row+3, col*2)) = (unsigned short)(p1 >> 16);
      }
    }
    __syncthreads();                                   // S2
    zero_acc(acc);
    gemm_waveB(sp_wb, Ss, acc, lane, c0w);
    // s = acc + sp_b -> As
    #pragma unroll
    for(int fc = 0; fc < 4; ++fc){
      const int col = c0w + fc*16 + lr;
      const float sb = sp_bv[col];
      #pragma unroll
      for(int fr = 0; fr < 4; ++fr){
        const int row = fr*16 + rb;
        unsigned p0 = pk_bf16(acc[fr][fc][0] + sb, acc[fr][fc][1] + sb);
        unsigned p1 = pk_bf16(acc[fr][fc][2] + sb, acc[fr][fc][3] + sb);
        *(unsigned short*)(As + swzA(row+0, col*2)) = (unsigned short)p0;
        *(unsigned short*)(As + swzA(row+1, col*2)) = (unsigned short)(p0 >> 16);
        *(unsigned short*)(As + swzA(row+2, col*2)) = (unsigned short)p1;
        *(unsigned short*)(As + swzA(row+3, col*2)) = (unsigned short)(p1 >> 16);
      }
    }
    __syncthreads();                                   // S3
    // ---- scan (thread = channel), chunked 16: batch reads, reg FMA chain, batch writes ----
    #pragma unroll
    for(int c4 = 0; c4 < 4; ++c4){
      const int base = c4*16;
      float v[16];
      #pragma unroll
      for(int j = 0; j < 16; ++j)
        v[j] = bf2f(*(const unsigned short*)(As + swzA(base+j, tid*2)));
      #pragma unroll
      for(int j = 0; j < 16; ++j){ st = st*dc + v[j]; v[j] = st; }
      #pragma unroll
      for(int j = 0; j < 8; ++j){
        unsigned p = pk_bf16(v[2*j], v[2*j+1]);
        *(unsigned short*)(As + swzA(base+2*j,   tid*2)) = (unsigned short)p;
        *(unsigned short*)(As + swzA(base+2*j+1, tid*2)) = (unsigned short)(p >> 16);
      }
    }
    __syncthreads();                                   // S4
    zero_acc(acc);
    gemm_waveB(spT_wb, As, acc, lane, c0w);            // y1 = states@sp_w
    __syncthreads();                                   // S5
    // y = acc + D*xg (xg from Ss) -> As
    #pragma unroll
    for(int fc = 0; fc < 4; ++fc){
      const int col = c0w + fc*16 + lr;
      const float Dv = D_v[col];
      #pragma unroll
      for(int fr = 0; fr < 4; ++fr){
        const int row = fr*16 + rb;
        float y0 = acc[fr][fc][0] + Dv*bf2f(*(const unsigned short*)(Ss + swzA(row+0, col*2)));
        float y1 = acc[fr][fc][1] + Dv*bf2f(*(const unsigned short*)(Ss + swzA(row+1, col*2)));
        float y2 = acc[fr][fc][2] + Dv*bf2f(*(const unsigned short*)(Ss + swzA(row+2, col*2)));
        float y3 = acc[fr][fc][3] + Dv*bf2f(*(const unsigned short*)(Ss + swzA(row+3, col*2)));
        unsigned p0 = pk_bf16(y0, y1), p1 = pk_bf16(y2, y3);
        *(unsigned short*)(As + swzA(row+0, col*2)) = (unsigned short)p0;
        *(unsigned short*)(As + swzA(row+1, col*2)) = (unsigned short)(p0 >> 16);
        *(unsigned short*)(As + swzA(row+2, col*2)) = (unsigned short)p1;
        *(unsigned short*)(As + swzA(row+3, col*2)) = (unsigned short)(p1 >> 16);
      }
    }
    __syncthreads();                                   // S6
    zero_acc(acc);
    gemm_waveB(op_wb, As, acc, lane, c0w);             // @op^T
    // acc + op_b -> Ss
    #pragma unroll
    for(int fc = 0; fc < 4; ++fc){
      const int col = c0w + fc*16 + lr;
      const float ob = op_bv[col];
      #pragma unroll
      for(int fr = 0; fr < 4; ++fr){
        const int row = fr*16 + rb;
        unsigned p0 = pk_bf16(acc[fr][fc][0] + ob, acc[fr][fc][1] + ob);
        unsigned p1 = pk_bf16(acc[fr][fc][2] + ob, acc[fr][fc][3] + ob);
        *(unsigned short*)(Ss + swzA(row+0, col*2)) = (unsigned short)p0;
        *(unsigned short*)(Ss + swzA(row+1, col*2)) = (unsigned short)(p0 >> 16);
        *(unsigned short*)(Ss + swzA(row+2, col*2)) = (unsigned short)p1;
        *(unsigned short*)(Ss + swzA(row+3, col*2)) = (unsigned short)(p1 >> 16);
      }
    }
    __syncthreads();                                   // S7
    // h += (y@op^T + op_b), coalesced RMW from Ss
    {
      char* dst = (char*)(h_g + (size_t)m0*DMODEL);
      #pragma unroll
      for(int i = 0; i < 8; ++i){
        const unsigned flat = (unsigned)(i*4096 + tid*16);
        const unsigned row = flat >> 9;
        short8 a = *(const short8*)(Ss + (flat ^ ((row & 7u) << 4)));
        short8 hv = *(const short8*)(dst + flat);
        uint4 o;
        unsigned pr[4];
        #pragma unroll
        for(int j = 0; j < 4; ++j){
          float s0 = bf2f((unsigned short)a[2*j])   + bf2f((unsigned short)hv[2*j]);
          float s1 = bf2f((unsigned short)a[2*j+1]) + bf2f((unsigned short)hv[2*j+1]);
          pr[j] = pk_bf16(s0, s1);
        }
        o.x = pr[0]; o.y = pr[1]; o.z = pr[2]; o.w = pr[3];
        *(uint4*)(dst + flat) = o;
      }
    }
    // next tile's Phase A writes As (last read pre-S7); S1 of next tile fences Ss
  }
  state_buf[n*256 + tid] = st;
}

// ---------------- out = gelu(LN(h[:,511,:] @ out_w^T + out_b)) (proven) ----------------
__global__ __launch_bounds__(256) void k_out(
    const unsigned short* __restrict__ h_g,
    const unsigned short* __restrict__ out_wb,
    const float* __restrict__ out_bv,
    const float* __restrict__ ln_gv, const float* __restrict__ ln_bv,
    float* __restrict__ out_g)
{
  __shared__ char smem[65536];
  char* As = smem; char* Bs = smem + 32768;
  const int tid = threadIdx.x;
  const int r0 = blockIdx.x * 64;
  const int lane = tid & 63, c0w = (tid>>6)*64, lr = lane & 15, rb = (lane>>4)*4;
  {
    const int r = tid >> 2, c0 = (tid & 3) * 64;
    const unsigned short* src = h_g + ((size_t)(r0 + r)*KSEQ + (KSEQ-1))*DMODEL + c0;
    #pragma unroll
    for(int i = 0; i < 8; ++i){
      short8 v = *(const short8*)(src + i*8);
      *(short8*)(As + swzA(r, c0*2 + i*16)) = v;
    }
  }
  f32x4 acc[4][4]; zero_acc(acc);
  gemm_64x256<4>(out_wb, As, Bs, acc, tid);
  __syncthreads();
  #pragma unroll
  for(int fc = 0; fc < 4; ++fc){
    const int col = c0w + fc*16 + lr;
    const float bb = out_bv[col];
    #pragma unroll
    for(int fr = 0; fr < 4; ++fr)
      #pragma unroll
      for(int rg = 0; rg < 4; ++rg){
        const int row = fr*16 + rb + rg;
        *(float*)(smem + (((unsigned)(row*1024 + col*4)) ^ ((row&7)<<4))) = acc[fr][fc][rg] + bb;
      }
  }
  __syncthreads();
  {
    const int r = tid >> 2, c0 = (tid & 3) * 64;
    float vals[64]; float sm = 0.f, sq = 0.f;
    #pragma unroll
    for(int i = 0; i < 16; ++i){
      float4 v = *(const float4*)(smem + (((unsigned)(r*1024 + (c0 + i*4)*4)) ^ ((r&7)<<4)));
      vals[4*i]=v.x; vals[4*i+1]=v.y; vals[4*i+2]=v.z; vals[4*i+3]=v.w;
    }
    #pragma unroll
    for(int i = 0; i < 64; ++i){ sm += vals[i]; sq += vals[i]*vals[i]; }
    sm += __shfl_xor(sm, 1); sm += __shfl_xor(sm, 2);
    sq += __shfl_xor(sq, 1); sq += __shfl_xor(sq, 2);
    const float mu = sm * (1.f/256.f);
    const float rstd = rsqrtf(sq * (1.f/256.f) - mu*mu + 1e-5f);
    float* dst = out_g + (size_t)(r0 + r)*DMODEL + c0;
    #pragma unroll
    for(int i = 0; i < 16; ++i){
      float4 o;
      o.x = gelu_f((vals[4*i+0]-mu)*rstd*ln_gv[c0+i*4+0] + ln_bv[c0+i*4+0]);
      o.y = gelu_f((vals[4*i+1]-mu)*rstd*ln_gv[c0+i*4+1] + ln_bv[c0+i*4+1]);
      o.z = gelu_f((vals[4*i+2]-mu)*rstd*ln_gv[c0+i*4+2] + ln_bv[c0+i*4+2]);
      o.w = gelu_f((vals[4*i+3]-mu)*rstd*ln_gv[c0+i*4+3] + ln_bv[c0+i*4+3]);
      *(float4*)(dst + i*4) = o;
    }
  }
}

extern "C" void kernel_launch(void* const* d_in, const int* in_sizes, int n_in,
                              void* d_out, int out_size, void* d_ws, size_t ws_size,
                              hipStream_t stream) {
  (void)in_sizes; (void)n_in; (void)out_size; (void)ws_size;
  const float* x        = (const float*)d_in[0];
  const float* in_w     = (const float*)d_in[1];
  const float* in_b     = (const float*)d_in[2];
  const float* in_ln_g  = (const float*)d_in[3];
  const float* in_ln_b  = (const float*)d_in[4];
  const float* ln_g     = (const float*)d_in[5];
  const float* ln_b     = (const float*)d_in[6];
  const float* gate_w   = (const float*)d_in[7];
  const float* gate_b   = (const float*)d_in[8];
  const float* sp_w     = (const float*)d_in[9];
  const float* sp_b     = (const float*)d_in[10];
  const float* op_w     = (const float*)d_in[11];
  const float* op_b     = (const float*)d_in[12];
  const float* A_log    = (const float*)d_in[13];
  const float* Dp       = (const float*)d_in[14];
  const float* out_w    = (const float*)d_in[15];
  const float* out_b    = (const float*)d_in[16];
  const float* out_ln_g = (const float*)d_in[17];
  const float* out_ln_b = (const float*)d_in[18];

  char* ws = (char*)d_ws;
  // ~133.7 MiB workspace (v2-proven budget)
  unsigned short* h_g       = (unsigned short*)(ws + 0);           // 128 MiB
  float*          state_buf = (float*)(ws + 134217728);            // 512 KiB
  float*          decay     = (float*)(ws + 134742016);            // 2 KiB
  unsigned short* wbase     = (unsigned short*)(ws + 134744064);   // ~1.2 MiB
  unsigned short* in_wb  = wbase;               // 32768
  unsigned short* gate_wb= in_wb  + 32768;      // 2*65536
  unsigned short* sp_wb  = gate_wb+ 131072;
  unsigned short* sp_wTb = sp_wb  + 131072;
  unsigned short* op_wb  = sp_wTb + 131072;
  unsigned short* out_wb = op_wb  + 131072;     // 65536

  // prep
  k_cvt_inw<<<128, 256, 0, stream>>>(in_w, in_wb);
  k_cvt<<<512, 256, 0, stream>>>(gate_w, gate_wb, 131072);
  k_cvt<<<512, 256, 0, stream>>>(sp_w,   sp_wb,   131072);
  k_cvt<<<512, 256, 0, stream>>>(op_w,   op_wb,   131072);
  k_cvt<<<256, 256, 0, stream>>>(out_w,  out_wb,  65536);
  k_spT<<<dim3(256,2), 256, 0, stream>>>(sp_w, sp_wTb);
  k_decay<<<2, 256, 0, stream>>>(A_log, decay);

  // pipeline
  k_in_proj<<<MTOT/64, 256, 0, stream>>>(x, in_wb, in_b, in_ln_g, in_ln_b, h_g);
  for(int l = 0; l < 2; ++l){
    k_layer<<<NSEQ, 256, 0, stream>>>(h_g,
        gate_wb + l*65536, sp_wb + l*65536, sp_wTb + l*65536, op_wb + l*65536,
        ln_g + l*256, ln_b + l*256, gate_b + l*256, sp_b + l*256,
        decay + l*256, Dp + l*256, op_b + l*256, state_buf, l);
  }
  k_out<<<NSEQ/64, 256, 0, stream>>>(h_g, out_wb, out_b, out_ln_g, out_ln_b, (float*)d_out);
}